// Round 1
// 117.837 us; speedup vs baseline: 1.1118x; 1.1118x over previous
//
#include <hip/hip_runtime.h>

// Problem constants (B=32, N=256, D=256 -> M=8192)
#define M_ROWS 8192
#define D_DIM  256
#define BM     128                // block tile rows (i / audio)
#define BN     128                // block tile cols (j / visual)
#define NBI    (M_ROWS / BM)      // 64 i-tiles
#define NBJ    (M_ROWS / BN)      // 64 j-tiles
#define NJOBS  (NBI * NBJ)        // 4096 gemm blocks

// Fold 1/TEMP * log2(e) into normalization: acc = log2(e)*sim/TEMP, e = exp2(acc)
#define ALPHA  4.53982478f        // sqrt(log2(e)/0.07)

// fp8 fragment layout for mfma_scale_f32_16x16x128_f8f6f4 (K=128 per MFMA):
//   tile16 = 16 rows x 256 k = 4 KB, at tile*4096
//   per k-step s (0/1, K=128 each): 2 KB chunk at +s*2048
//   within chunk: half h (0/1) at +h*1024, then lane*16 bytes
//   lane l holds row (l&15), k = s*128 + (l>>4)*32 + h*16 + byte(0..15)
// => every load/store/ds op is 64 lanes x 16 B fully contiguous (stride-16).

typedef __attribute__((ext_vector_type(4))) float floatx4;  // MFMA C/D
typedef __attribute__((ext_vector_type(8))) int   intx8;    // MFMA A/B (32 B fp8)

__device__ inline float fast_exp2(float x) {
#if __has_builtin(__builtin_amdgcn_exp2f)
    return __builtin_amdgcn_exp2f(x);
#else
    return exp2f(x);
#endif
}

// MX-scaled fp8 MFMA with unit scales (E8M0 bias 127 -> 2^0). cbsz/blgp = 0 = OCP e4m3.
__device__ inline floatx4 mfma_fp8(intx8 a, intx8 b, floatx4 c) {
    return __builtin_amdgcn_mfma_scale_f32_16x16x128_f8f6f4(
        a, b, c, 0, 0, 0, 0x7f7f7f7f, 0, 0x7f7f7f7f);
}

// Kernel 1: L2-normalize, scale by ALPHA, emit fp8 e4m3 in fragment order.
// Each thread loads exactly the 16 f32 it emits (64 B contiguous); only the
// row-norm is cross-thread (2 shuffles + tiny LDS). Output store = dst + t*16,
// fully coalesced. Block 0 zeroes the finalize accumulators.
__global__ __launch_bounds__(256) void normalize_kernel(
    const float* __restrict__ af, const float* __restrict__ vf,
    unsigned char* __restrict__ aB, unsigned char* __restrict__ vB,
    float* __restrict__ glob)
{
    __shared__ float ssb[16][4];

    if (blockIdx.x == 0) {
        if (threadIdx.x < 4) glob[threadIdx.x] = 0.f;
        if (threadIdx.x == 4) ((int*)glob)[4] = 0;
    }

    const int b = blockIdx.x;            // 0..1023
    const bool isA = b < 512;
    const int T = isA ? b : b - 512;     // tile16 index 0..511
    const float* src = (isA ? af : vf) + (size_t)T * 16 * D_DIM;
    unsigned char* dst = (isA ? aB : vB) + (size_t)T * 4096;

    const int t    = threadIdx.x;
    const int wave = t >> 6, lane = t & 63;
    const int row  = t & 15;             // == lane & 15
    const int kq   = (t >> 4) & 3;
    const int h    = (t >> 6) & 1;
    const int s    = t >> 7;
    const int kbase = s * 128 + kq * 32 + h * 16;

    const float* p = src + row * D_DIM + kbase;
    float4 x0 = ((const float4*)p)[0], x1 = ((const float4*)p)[1];
    float4 x2 = ((const float4*)p)[2], x3 = ((const float4*)p)[3];

    float ss = x0.x*x0.x + x0.y*x0.y + x0.z*x0.z + x0.w*x0.w
             + x1.x*x1.x + x1.y*x1.y + x1.z*x1.z + x1.w*x1.w
             + x2.x*x2.x + x2.y*x2.y + x2.z*x2.z + x2.w*x2.w
             + x3.x*x3.x + x3.y*x3.y + x3.z*x3.z + x3.w*x3.w;
    // within a wave, lanes differing in bits 4..5 are the 4 kq groups of this row
    ss += __shfl_xor(ss, 16, 64);
    ss += __shfl_xor(ss, 32, 64);
    if (lane < 16) ssb[lane][wave] = ss;
    __syncthreads();
    float tot = ssb[row][0] + ssb[row][1] + ssb[row][2] + ssb[row][3];
    float scale = ALPHA / fmaxf(sqrtf(tot), 1e-12f);

    int4 o;
    int pk;
    pk  = __builtin_amdgcn_cvt_pk_fp8_f32(x0.x*scale, x0.y*scale, 0, false);
    pk  = __builtin_amdgcn_cvt_pk_fp8_f32(x0.z*scale, x0.w*scale, pk, true);
    o.x = pk;
    pk  = __builtin_amdgcn_cvt_pk_fp8_f32(x1.x*scale, x1.y*scale, 0, false);
    pk  = __builtin_amdgcn_cvt_pk_fp8_f32(x1.z*scale, x1.w*scale, pk, true);
    o.y = pk;
    pk  = __builtin_amdgcn_cvt_pk_fp8_f32(x2.x*scale, x2.y*scale, 0, false);
    pk  = __builtin_amdgcn_cvt_pk_fp8_f32(x2.z*scale, x2.w*scale, pk, true);
    o.z = pk;
    pk  = __builtin_amdgcn_cvt_pk_fp8_f32(x3.x*scale, x3.y*scale, 0, false);
    pk  = __builtin_amdgcn_cvt_pk_fp8_f32(x3.z*scale, x3.w*scale, pk, true);
    o.w = pk;
    *(int4*)(dst + (size_t)t * 16) = o;
}

// Kernel 2: fused GEMM (acc = log2e*sim/T) via MX-scaled fp8 K=128 MFMA,
// exp2 + (total,class1) row/col sums. Block 128x128, 4 waves, wave tile 32x128.
// B tile (32 KB) staged once in LDS (shared by all 4 waves -> L2 traffic 64 KB
// per block instead of 160 KB); A fragments loaded direct, all issued upfront.
__global__ __launch_bounds__(256, 3) void gemm_loss_kernel(
    const unsigned char* __restrict__ aB, const unsigned char* __restrict__ vB,
    const int* __restrict__ la, const int* __restrict__ lv,
    float* __restrict__ rowPart, float* __restrict__ colPart)
{
    __shared__ unsigned char ldsB[32768];       // 8 tile16 x 4 KB, fragment-linear
    __shared__ float rowbuf[2 * BM];            // 1 KB
    __shared__ float colbuf[8 * BN];            // 4 KB

    const int tid  = threadIdx.x;
    const int wave = tid >> 6, lane = tid & 63;
    const int quad = lane >> 4, l16 = lane & 15;

    // supertile swizzle: 16 supers x 256 inner -> 16x16 tile regions (L2 locality)
    const int super = blockIdx.x >> 8;          // 0..15
    const int inner = blockIdx.x & 255;
    const int bx = (super & 3) * 16 + (inner & 15);    // 0..63 (i-tile)
    const int by = (super >> 2) * 16 + (inner >> 4);   // 0..63 (j-tile)
    const int i0 = bx * BM, j0 = by * BN;

    // ---- stage B tile into LDS (layout == global fragment layout, stride-16)
    {
        const unsigned char* vsrc = vB + (size_t)by * 32768 + (size_t)wave * 8192
                                       + (size_t)lane * 16;
        unsigned char* ldst = ldsB + wave * 8192 + lane * 16;
        #pragma unroll
        for (int c = 0; c < 8; ++c)
            *(int4*)(ldst + c * 1024) = *(const int4*)(vsrc + c * 1024);
    }

    // ---- A fragments [it][s]: 32 B each, halves at +0 / +1024
    const unsigned char* Abase = aB + (size_t)(bx * 8 + wave * 2) * 4096
                                    + (size_t)lane * 16;
    intx8 afr[2][2];
    #pragma unroll
    for (int it = 0; it < 2; ++it) {
        #pragma unroll
        for (int s = 0; s < 2; ++s) {
            int4 h0 = *(const int4*)(Abase + it * 4096 + s * 2048);
            int4 h1 = *(const int4*)(Abase + it * 4096 + s * 2048 + 1024);
            afr[it][s] = intx8{h0.x, h0.y, h0.z, h0.w, h1.x, h1.y, h1.z, h1.w};
        }
    }

    __syncthreads();

    // ---- main loop: 2 k-steps x 8 j-tiles, 2 MFMAs per B fragment
    floatx4 acc[2][8] = {};
    const unsigned char* Bl = ldsB + lane * 16;
    #pragma unroll
    for (int s = 0; s < 2; ++s) {
        #pragma unroll
        for (int jt = 0; jt < 8; ++jt) {
            int4 h0 = *(const int4*)(Bl + jt * 4096 + s * 2048);
            int4 h1 = *(const int4*)(Bl + jt * 4096 + s * 2048 + 1024);
            intx8 bf = intx8{h0.x, h0.y, h0.z, h0.w, h1.x, h1.y, h1.z, h1.w};
            acc[0][jt] = mfma_fp8(afr[0][s], bf, acc[0][jt]);
            acc[1][jt] = mfma_fp8(afr[1][s], bf, acc[1][jt]);
        }
    }

    // ---- epilogue: exp2 + (total, class1); C/D: col = l16, row = quad*4 + r
    const int baseRow = i0 + wave * 32;
    float maf[2][4];
    #pragma unroll
    for (int it = 0; it < 2; ++it)
        #pragma unroll
        for (int r = 0; r < 4; ++r)
            maf[it][r] = (float)la[baseRow + it * 16 + quad * 4 + r];
    float mvf[8];
    #pragma unroll
    for (int jt = 0; jt < 8; ++jt)
        mvf[jt] = (float)lv[j0 + jt * 16 + l16];

    float rT[2][4] = {}, r1[2][4] = {};
    float cT[8] = {}, c1[8] = {};
    #pragma unroll
    for (int it = 0; it < 2; ++it) {
        #pragma unroll
        for (int jt = 0; jt < 8; ++jt) {
            #pragma unroll
            for (int r = 0; r < 4; ++r) {
                float e = fast_exp2(acc[it][jt][r]);
                rT[it][r] += e;
                r1[it][r] = fmaf(mvf[jt], e, r1[it][r]);
                cT[jt] += e;
                c1[jt] = fmaf(maf[it][r], e, c1[jt]);
            }
        }
    }

    // col sums: reduce over quads within wave (register-only)
    #pragma unroll
    for (int jt = 0; jt < 8; ++jt) {
        float t0 = cT[jt], t1 = c1[jt];
        t0 += __shfl_xor(t0, 16, 64); t0 += __shfl_xor(t0, 32, 64);
        t1 += __shfl_xor(t1, 16, 64); t1 += __shfl_xor(t1, 32, 64);
        cT[jt] = t0; c1[jt] = t1;
    }

    // row sums: reduce over the quad's 16 lanes (cols), stage in LDS
    #pragma unroll
    for (int it = 0; it < 2; ++it) {
        #pragma unroll
        for (int r = 0; r < 4; ++r) {
            float s0 = rT[it][r], s1 = r1[it][r];
            #pragma unroll
            for (int m = 1; m < 16; m <<= 1) {
                s0 += __shfl_xor(s0, m, 64);
                s1 += __shfl_xor(s1, m, 64);
            }
            if (l16 == 0) {
                int rl = wave * 32 + it * 16 + quad * 4 + r;   // 0..127
                rowbuf[rl * 2 + 0] = s0;
                rowbuf[rl * 2 + 1] = s1;
            }
        }
    }
    if (quad == 0) {
        #pragma unroll
        for (int jt = 0; jt < 8; ++jt) {
            colbuf[(wave * 2 + 0) * BN + jt * 16 + l16] = cT[jt];
            colbuf[(wave * 2 + 1) * BN + jt * 16 + l16] = c1[jt];
        }
    }
    __syncthreads();

    // coalesced per-block partial writes (256 floats each)
    {
        const int rl  = tid >> 1;      // 0..127
        const int cls = tid & 1;
        rowPart[((size_t)by * M_ROWS + i0 + rl) * 2 + cls] = rowbuf[rl * 2 + cls];
        float s = colbuf[(0 * 2 + cls) * BN + rl] + colbuf[(1 * 2 + cls) * BN + rl]
                + colbuf[(2 * 2 + cls) * BN + rl] + colbuf[(3 * 2 + cls) * BN + rl];
        colPart[((size_t)bx * M_ROWS + j0 + rl) * 2 + cls] = s;
    }
}

// Kernel 3: reduce partials over 64 slabs, per-row/col log terms, then merged
// finalize: per-block (sum,count) -> device atomicAdd; last block (atomic
// counter) computes the final scalar. Blocks 0..31 = rows, 32..63 = cols.
// glob: [sumA, cntA, sumV, cntV, (int)counter] - zeroed by normalize block 0.
__global__ __launch_bounds__(256) void reduce_kernel(
    const float* __restrict__ rowPart, const float* __restrict__ colPart,
    const int* __restrict__ la, const int* __restrict__ lv,
    float* __restrict__ glob, float* __restrict__ out)
{
    const int bid = blockIdx.x;
    const bool aside = bid < 32;
    const int idx = (aside ? bid : bid - 32) * 256 + threadIdx.x;   // row or col index
    const float* part = aside ? rowPart : colPart;
    const int* lab = aside ? la : lv;

    float tot = 0.f, c1 = 0.f;
    #pragma unroll 4
    for (int b = 0; b < 64; ++b) {
        float2 p = *(const float2*)(part + ((size_t)b * M_ROWS + idx) * 2);
        tot += p.x; c1 += p.y;
    }
    float num = lab[idx] ? c1 : 0.1f * (tot - c1);
    float lg = 0.f, cnt = 0.f;
    if (num > 0.f) { lg = logf((num + 1e-8f) / (tot + 1e-8f)); cnt = 1.f; }

    #pragma unroll
    for (int m = 1; m < 64; m <<= 1) {
        lg  += __shfl_xor(lg,  m, 64);
        cnt += __shfl_xor(cnt, m, 64);
    }
    __shared__ float red[4][2];
    const int w = threadIdx.x >> 6, ln = threadIdx.x & 63;
    if (ln == 0) { red[w][0] = lg; red[w][1] = cnt; }
    __syncthreads();
    if (threadIdx.x == 0) {
        float slg  = red[0][0] + red[1][0] + red[2][0] + red[3][0];
        float scnt = red[0][1] + red[1][1] + red[2][1] + red[3][1];
        float* base = glob + (aside ? 0 : 2);
        atomicAdd(&base[0], slg);
        atomicAdd(&base[1], scnt);
        __threadfence();
        int old = atomicAdd((int*)glob + 4, 1);
        if (old == 63) {
            __threadfence();
            float sA = atomicAdd(&glob[0], 0.f);
            float cA = atomicAdd(&glob[1], 0.f);
            float sV = atomicAdd(&glob[2], 0.f);
            float cV = atomicAdd(&glob[3], 0.f);
            float lossA = -sA / fmaxf(cA, 1.f);
            float lossV = -sV / fmaxf(cV, 1.f);
            out[0] = 0.5f * (lossA + lossV);
        }
    }
}

extern "C" void kernel_launch(void* const* d_in, const int* in_sizes, int n_in,
                              void* d_out, int out_size, void* d_ws, size_t ws_size,
                              hipStream_t stream)
{
    const float* af = (const float*)d_in[0];
    const float* vf = (const float*)d_in[1];
    const int*   la = (const int*)d_in[2];
    const int*   lv = (const int*)d_in[3];
    float* out = (float*)d_out;

    char* ws = (char*)d_ws;
    unsigned char* aB = (unsigned char*)ws;                            // 2 MiB (fp8 fragment order)
    unsigned char* vB = (unsigned char*)(ws + 2ull * 1024 * 1024);     // 2 MiB
    float* rowPart   = (float*)(ws +  4ull * 1024 * 1024);             // 4 MiB [64][8192][2]
    float* colPart   = (float*)(ws +  8ull * 1024 * 1024);             // 4 MiB [64][8192][2]
    float* glob      = (float*)(ws + 12ull * 1024 * 1024);             // 4 floats + counter

    normalize_kernel<<<1024, 256, 0, stream>>>(af, vf, aB, vB, glob);
    gemm_loss_kernel<<<NJOBS, 256, 0, stream>>>(aB, vB, la, lv, rowPart, colPart);
    reduce_kernel<<<64, 256, 0, stream>>>(rowPart, colPart, la, lv, glob, out);
}

// Round 3
// 113.751 us; speedup vs baseline: 1.1517x; 1.0359x over previous
//
#include <hip/hip_runtime.h>

// Problem constants (B=32, N=256, D=256 -> M=8192)
#define M_ROWS 8192
#define D_DIM  256
#define BM     256                // block tile rows (i / audio)
#define BN     128                // block tile cols (j / visual)
#define NBI    (M_ROWS / BM)      // 32 i-tiles
#define NBJ    (M_ROWS / BN)      // 64 j-tiles
#define NJOBS  (NBI * NBJ)        // 2048 gemm blocks

// Fold 1/TEMP * log2(e) into normalization: acc = log2(e)*sim/TEMP, e = exp2(acc)
#define ALPHA  4.53982478f        // sqrt(log2(e)/0.07)

// fp8 fragment layout for mfma_scale_f32_16x16x128_f8f6f4 (K=128 per MFMA):
//   tile16 = 16 rows x 256 k = 4 KB, at tile*4096
//   per k-step s (0/1, K=128 each): 2 KB chunk at +s*2048
//   within chunk: half h (0/1) at +h*1024, then lane*16 bytes
//   lane l holds row (l&15), k = s*128 + (l>>4)*32 + h*16 + byte(0..15)
// => every load/store/ds op is 64 lanes x 16 B fully contiguous (stride-16).

typedef __attribute__((ext_vector_type(4))) float floatx4;  // MFMA C/D
typedef __attribute__((ext_vector_type(8))) int   intx8;    // MFMA A/B (32 B fp8)

__device__ inline float fast_exp2(float x) {
#if __has_builtin(__builtin_amdgcn_exp2f)
    return __builtin_amdgcn_exp2f(x);
#else
    return exp2f(x);
#endif
}

// MX-scaled fp8 MFMA with unit scales (E8M0 bias 127 -> 2^0). cbsz/blgp = 0 = OCP e4m3.
__device__ inline floatx4 mfma_fp8(intx8 a, intx8 b, floatx4 c) {
    return __builtin_amdgcn_mfma_scale_f32_16x16x128_f8f6f4(
        a, b, c, 0, 0, 0, 0x7f7f7f7f, 0, 0x7f7f7f7f);
}

// Kernel 1: L2-normalize, scale by ALPHA, emit fp8 e4m3 in fragment order.
// Each thread loads exactly the 16 f32 it emits (64 B contiguous); only the
// row-norm is cross-thread (2 shuffles + tiny LDS). Output store = dst + t*16,
// fully coalesced. Block 0 zeroes the finalize accumulators.
__global__ __launch_bounds__(256) void normalize_kernel(
    const float* __restrict__ af, const float* __restrict__ vf,
    unsigned char* __restrict__ aB, unsigned char* __restrict__ vB,
    float* __restrict__ glob)
{
    __shared__ float ssb[16][4];

    if (blockIdx.x == 0) {
        if (threadIdx.x < 4) glob[threadIdx.x] = 0.f;
        if (threadIdx.x == 4) ((int*)glob)[4] = 0;
    }

    const int b = blockIdx.x;            // 0..1023
    const bool isA = b < 512;
    const int T = isA ? b : b - 512;     // tile16 index 0..511
    const float* src = (isA ? af : vf) + (size_t)T * 16 * D_DIM;
    unsigned char* dst = (isA ? aB : vB) + (size_t)T * 4096;

    const int t    = threadIdx.x;
    const int wave = t >> 6, lane = t & 63;
    const int row  = t & 15;             // == lane & 15
    const int kq   = (t >> 4) & 3;
    const int h    = (t >> 6) & 1;
    const int s    = t >> 7;
    const int kbase = s * 128 + kq * 32 + h * 16;

    const float* p = src + row * D_DIM + kbase;
    float4 x0 = ((const float4*)p)[0], x1 = ((const float4*)p)[1];
    float4 x2 = ((const float4*)p)[2], x3 = ((const float4*)p)[3];

    float ss = x0.x*x0.x + x0.y*x0.y + x0.z*x0.z + x0.w*x0.w
             + x1.x*x1.x + x1.y*x1.y + x1.z*x1.z + x1.w*x1.w
             + x2.x*x2.x + x2.y*x2.y + x2.z*x2.z + x2.w*x2.w
             + x3.x*x3.x + x3.y*x3.y + x3.z*x3.z + x3.w*x3.w;
    // within a wave, lanes differing in bits 4..5 are the 4 kq groups of this row
    ss += __shfl_xor(ss, 16, 64);
    ss += __shfl_xor(ss, 32, 64);
    if (lane < 16) ssb[lane][wave] = ss;
    __syncthreads();
    float tot = ssb[row][0] + ssb[row][1] + ssb[row][2] + ssb[row][3];
    float scale = ALPHA / fmaxf(sqrtf(tot), 1e-12f);

    int4 o;
    int pk;
    pk  = __builtin_amdgcn_cvt_pk_fp8_f32(x0.x*scale, x0.y*scale, 0, false);
    pk  = __builtin_amdgcn_cvt_pk_fp8_f32(x0.z*scale, x0.w*scale, pk, true);
    o.x = pk;
    pk  = __builtin_amdgcn_cvt_pk_fp8_f32(x1.x*scale, x1.y*scale, 0, false);
    pk  = __builtin_amdgcn_cvt_pk_fp8_f32(x1.z*scale, x1.w*scale, pk, true);
    o.y = pk;
    pk  = __builtin_amdgcn_cvt_pk_fp8_f32(x2.x*scale, x2.y*scale, 0, false);
    pk  = __builtin_amdgcn_cvt_pk_fp8_f32(x2.z*scale, x2.w*scale, pk, true);
    o.z = pk;
    pk  = __builtin_amdgcn_cvt_pk_fp8_f32(x3.x*scale, x3.y*scale, 0, false);
    pk  = __builtin_amdgcn_cvt_pk_fp8_f32(x3.z*scale, x3.w*scale, pk, true);
    o.w = pk;
    *(int4*)(dst + (size_t)t * 16) = o;
}

// Kernel 2: fused GEMM (acc = log2e*sim/T) via MX-scaled fp8 K=128 MFMA,
// exp2 + (total,class1) row/col sums. Block 256x128, 8 waves, wave tile 32x128.
// B tile (32 KB) staged once in LDS, shared by all 8 waves (L2 traffic 96 KB
// per 32K outputs vs 64 KB per 16K before = -25% total); A direct to regs.
__global__ __launch_bounds__(512, 4) void gemm_loss_kernel(
    const unsigned char* __restrict__ aB, const unsigned char* __restrict__ vB,
    const int* __restrict__ la, const int* __restrict__ lv,
    float* __restrict__ rowPart, float* __restrict__ colPart)
{
    __shared__ unsigned char ldsB[32768];       // 8 tile16 x 4 KB, fragment-linear
    __shared__ float rowbuf[2 * BM];            // 2 KB
    __shared__ float colbuf[16 * BN];           // [8 waves][2][128] = 8 KB

    const int tid  = threadIdx.x;
    const int wave = tid >> 6, lane = tid & 63;
    const int quad = lane >> 4, l16 = lane & 15;

    // supertile swizzle: 8 supers x 256 inner -> 16x16 tile regions (L2 locality)
    const int super = blockIdx.x >> 8;          // 0..7
    const int inner = blockIdx.x & 255;
    const int bx = (super & 1) * 16 + (inner & 15);    // 0..31 (i-tile of 256 rows)
    const int by = (super >> 1) * 16 + (inner >> 4);   // 0..63 (j-tile of 128 cols)
    const int i0 = bx * BM, j0 = by * BN;

    // ---- stage B tile into LDS (layout == global fragment layout, stride-16)
    {
        const unsigned char* vsrc = vB + (size_t)by * 32768 + (size_t)tid * 16;
        unsigned char* ldst = ldsB + tid * 16;
        #pragma unroll
        for (int c = 0; c < 4; ++c)
            *(int4*)(ldst + c * 8192) = *(const int4*)(vsrc + c * 8192);
    }

    // ---- A fragments [it][s]: 32 B each, halves at +0 / +1024
    const unsigned char* Abase = aB + (size_t)(bx * 16 + wave * 2) * 4096
                                    + (size_t)lane * 16;
    intx8 afr[2][2];
    #pragma unroll
    for (int it = 0; it < 2; ++it) {
        #pragma unroll
        for (int s = 0; s < 2; ++s) {
            int4 h0 = *(const int4*)(Abase + it * 4096 + s * 2048);
            int4 h1 = *(const int4*)(Abase + it * 4096 + s * 2048 + 1024);
            afr[it][s] = intx8{h0.x, h0.y, h0.z, h0.w, h1.x, h1.y, h1.z, h1.w};
        }
    }

    __syncthreads();

    // ---- main loop: 2 k-steps x 8 j-tiles, 2 MFMAs per B fragment
    floatx4 acc[2][8] = {};
    const unsigned char* Bl = ldsB + lane * 16;
    #pragma unroll
    for (int s = 0; s < 2; ++s) {
        #pragma unroll
        for (int jt = 0; jt < 8; ++jt) {
            int4 h0 = *(const int4*)(Bl + jt * 4096 + s * 2048);
            int4 h1 = *(const int4*)(Bl + jt * 4096 + s * 2048 + 1024);
            intx8 bf = intx8{h0.x, h0.y, h0.z, h0.w, h1.x, h1.y, h1.z, h1.w};
            acc[0][jt] = mfma_fp8(afr[0][s], bf, acc[0][jt]);
            acc[1][jt] = mfma_fp8(afr[1][s], bf, acc[1][jt]);
        }
    }

    // ---- epilogue: exp2 + (total, class1); C/D: col = l16, row = quad*4 + r
    const int baseRow = i0 + wave * 32;
    float maf[2][4];
    #pragma unroll
    for (int it = 0; it < 2; ++it)
        #pragma unroll
        for (int r = 0; r < 4; ++r)
            maf[it][r] = (float)la[baseRow + it * 16 + quad * 4 + r];
    float mvf[8];
    #pragma unroll
    for (int jt = 0; jt < 8; ++jt)
        mvf[jt] = (float)lv[j0 + jt * 16 + l16];

    float rT[2][4] = {}, r1[2][4] = {};
    float cT[8] = {}, c1[8] = {};
    #pragma unroll
    for (int it = 0; it < 2; ++it) {
        #pragma unroll
        for (int jt = 0; jt < 8; ++jt) {
            #pragma unroll
            for (int r = 0; r < 4; ++r) {
                float e = fast_exp2(acc[it][jt][r]);
                rT[it][r] += e;
                r1[it][r] = fmaf(mvf[jt], e, r1[it][r]);
                cT[jt] += e;
                c1[jt] = fmaf(maf[it][r], e, c1[jt]);
            }
        }
    }

    // col sums: reduce over quads within wave (register-only)
    #pragma unroll
    for (int jt = 0; jt < 8; ++jt) {
        float t0 = cT[jt], t1 = c1[jt];
        t0 += __shfl_xor(t0, 16, 64); t0 += __shfl_xor(t0, 32, 64);
        t1 += __shfl_xor(t1, 16, 64); t1 += __shfl_xor(t1, 32, 64);
        cT[jt] = t0; c1[jt] = t1;
    }

    // row sums: reduce over the quad's 16 lanes (cols), stage in LDS
    #pragma unroll
    for (int it = 0; it < 2; ++it) {
        #pragma unroll
        for (int r = 0; r < 4; ++r) {
            float s0 = rT[it][r], s1 = r1[it][r];
            #pragma unroll
            for (int m = 1; m < 16; m <<= 1) {
                s0 += __shfl_xor(s0, m, 64);
                s1 += __shfl_xor(s1, m, 64);
            }
            if (l16 == 0) {
                int rl = wave * 32 + it * 16 + quad * 4 + r;   // 0..255
                rowbuf[rl * 2 + 0] = s0;
                rowbuf[rl * 2 + 1] = s1;
            }
        }
    }
    if (quad == 0) {
        #pragma unroll
        for (int jt = 0; jt < 8; ++jt) {
            colbuf[(wave * 2 + 0) * BN + jt * 16 + l16] = cT[jt];
            colbuf[(wave * 2 + 1) * BN + jt * 16 + l16] = c1[jt];
        }
    }
    __syncthreads();

    // coalesced per-block partial writes
    {
        const int rl  = tid >> 1;      // 0..255
        const int cls = tid & 1;
        rowPart[((size_t)by * M_ROWS + i0 + rl) * 2 + cls] = rowbuf[rl * 2 + cls];
        if (tid < 256) {
            const int cl = tid >> 1;   // 0..127
            float s = 0.f;
            #pragma unroll
            for (int w = 0; w < 8; ++w)
                s += colbuf[(w * 2 + cls) * BN + cl];
            colPart[((size_t)bx * M_ROWS + j0 + cl) * 2 + cls] = s;
        }
    }
}

// Kernel 3: reduce partials (64 row-slabs / 32 col-slabs), per-row/col log
// terms, then merged finalize: per-block (sum,count) -> device atomicAdd; last
// block (atomic counter) computes the final scalar. Blocks 0..31 = rows,
// 32..63 = cols. glob: [sumA, cntA, sumV, cntV, (int)counter].
__global__ __launch_bounds__(256) void reduce_kernel(
    const float* __restrict__ rowPart, const float* __restrict__ colPart,
    const int* __restrict__ la, const int* __restrict__ lv,
    float* __restrict__ glob, float* __restrict__ out)
{
    const int bid = blockIdx.x;
    const bool aside = bid < 32;
    const int idx = (aside ? bid : bid - 32) * 256 + threadIdx.x;   // row or col index
    const float* part = aside ? rowPart : colPart;
    const int* lab = aside ? la : lv;
    const int nslab = aside ? 64 : 32;

    float tot = 0.f, c1 = 0.f;
    #pragma unroll 4
    for (int b = 0; b < nslab; ++b) {
        float2 p = *(const float2*)(part + ((size_t)b * M_ROWS + idx) * 2);
        tot += p.x; c1 += p.y;
    }
    float num = lab[idx] ? c1 : 0.1f * (tot - c1);
    float lg = 0.f, cnt = 0.f;
    if (num > 0.f) { lg = logf((num + 1e-8f) / (tot + 1e-8f)); cnt = 1.f; }

    #pragma unroll
    for (int m = 1; m < 64; m <<= 1) {
        lg  += __shfl_xor(lg,  m, 64);
        cnt += __shfl_xor(cnt, m, 64);
    }
    __shared__ float red[4][2];
    const int w = threadIdx.x >> 6, ln = threadIdx.x & 63;
    if (ln == 0) { red[w][0] = lg; red[w][1] = cnt; }
    __syncthreads();
    if (threadIdx.x == 0) {
        float slg  = red[0][0] + red[1][0] + red[2][0] + red[3][0];
        float scnt = red[0][1] + red[1][1] + red[2][1] + red[3][1];
        float* base = glob + (aside ? 0 : 2);
        atomicAdd(&base[0], slg);
        atomicAdd(&base[1], scnt);
        __threadfence();
        int old = atomicAdd((int*)glob + 4, 1);
        if (old == 63) {
            __threadfence();
            float sA = atomicAdd(&glob[0], 0.f);
            float cA = atomicAdd(&glob[1], 0.f);
            float sV = atomicAdd(&glob[2], 0.f);
            float cV = atomicAdd(&glob[3], 0.f);
            float lossA = -sA / fmaxf(cA, 1.f);
            float lossV = -sV / fmaxf(cV, 1.f);
            out[0] = 0.5f * (lossA + lossV);
        }
    }
}

extern "C" void kernel_launch(void* const* d_in, const int* in_sizes, int n_in,
                              void* d_out, int out_size, void* d_ws, size_t ws_size,
                              hipStream_t stream)
{
    const float* af = (const float*)d_in[0];
    const float* vf = (const float*)d_in[1];
    const int*   la = (const int*)d_in[2];
    const int*   lv = (const int*)d_in[3];
    float* out = (float*)d_out;

    char* ws = (char*)d_ws;
    unsigned char* aB = (unsigned char*)ws;                            // 2 MiB (fp8 fragment order)
    unsigned char* vB = (unsigned char*)(ws + 2ull * 1024 * 1024);     // 2 MiB
    float* rowPart   = (float*)(ws +  4ull * 1024 * 1024);             // 4 MiB [64][8192][2]
    float* colPart   = (float*)(ws +  8ull * 1024 * 1024);             // 2 MiB [32][8192][2]
    float* glob      = (float*)(ws + 12ull * 1024 * 1024);             // 4 floats + counter

    normalize_kernel<<<1024, 256, 0, stream>>>(af, vf, aB, vB, glob);
    gemm_loss_kernel<<<NJOBS, 512, 0, stream>>>(aB, vB, la, lv, rowPart, colPart);
    reduce_kernel<<<64, 256, 0, stream>>>(rowPart, colPart, la, lv, glob, out);
}